// Round 8
// baseline (27.775 us; speedup 1.0000x reference)
//
#include <hip/hip_runtime.h>

#define BSZ 64
#define LMAX 128
#define DIM 2048
#define NPOS (BSZ * LMAX)   // 8192

struct Ctrl {
    float accum;   // loss sum
    int   count;   // valid-pair count
    int   done2;   // finished loss-blocks
};

// ---------------- kernel 1: projections (+ ctrl init) ----------------
// 1024 blocks x 512 threads = 8 waves. Wave-pair owns 2 positions; each wave
// covers half a row (1024 dims) with its W-slice in REGISTERS (16 float4).
// ~114 VGPR -> no spill under the 128 cap of __launch_bounds__(512,4).
// Halves write separate proj buffers; loss sums them.
__global__ __launch_bounds__(512, 4) void proj_kernel(
        const float* __restrict__ enc,
        const float* __restrict__ W,
        float* __restrict__ proj,      // [2][NPOS][4] floats
        Ctrl* __restrict__ ctrl) {
    if (blockIdx.x == 0 && threadIdx.x == 0) {
        ctrl->accum = 0.f; ctrl->count = 0; ctrl->done2 = 0;
    }

    const int tid  = threadIdx.x;
    const int wid  = tid >> 6;
    const int lane = tid & 63;
    const int pair = wid >> 1;                      // 0..3
    const int half = wid & 1;                       // 0..1
    const int p0   = blockIdx.x * 8 + pair * 2;     // first of 2 positions

    // ---- W slice into registers: idx(it) = half*256 + it*64 + lane ----
    const float4* __restrict__ W4 = (const float4*)W;   // [2*DIM,2] row-major
    float4 wl0[4], wl1[4], wr0[4], wr1[4];
    #pragma unroll
    for (int it = 0; it < 4; ++it) {
        const int idx = half * 256 + it * 64 + lane;
        wl0[it] = W4[idx * 2];
        wl1[it] = W4[idx * 2 + 1];
        wr0[it] = W4[1024 + idx * 2];
        wr1[it] = W4[1024 + idx * 2 + 1];
    }

    float a0[2], a1[2], a2[2], a3[2];
    #pragma unroll
    for (int q = 0; q < 2; ++q) { a0[q] = a1[q] = a2[q] = a3[q] = 0.f; }

    const float4* __restrict__ h4 = (const float4*)enc;
    const size_t base = (size_t)p0 * (DIM / 4) + half * 256 + lane;

    // prefetch position 0
    float4 hq[4];
    #pragma unroll
    for (int it = 0; it < 4; ++it) hq[it] = h4[base + it * 64];

    #pragma unroll
    for (int q = 0; q < 2; ++q) {
        float4 hn[4];
        if (q == 0) {
            #pragma unroll
            for (int it = 0; it < 4; ++it)
                hn[it] = h4[base + (size_t)(DIM / 4) + it * 64];
        }
        #pragma unroll
        for (int it = 0; it < 4; ++it) {
            const float4 h = hq[it];
            a0[q] += h.x * wl0[it].x + h.y * wl0[it].z + h.z * wl1[it].x + h.w * wl1[it].z;
            a1[q] += h.x * wl0[it].y + h.y * wl0[it].w + h.z * wl1[it].y + h.w * wl1[it].w;
            a2[q] += h.x * wr0[it].x + h.y * wr0[it].z + h.z * wr1[it].x + h.w * wr1[it].z;
            a3[q] += h.x * wr0[it].y + h.y * wr0[it].w + h.z * wr1[it].y + h.w * wr1[it].w;
        }
        if (q == 0) {
            #pragma unroll
            for (int it = 0; it < 4; ++it) hq[it] = hn[it];
        }
    }

    // ---- reduce: fold 4 accs into lane residue (3 shfl-steps), then butterfly ----
    float* __restrict__ projf = proj + (size_t)half * NPOS * 4;
    #pragma unroll
    for (int q = 0; q < 2; ++q) {
        const bool o1 = (lane & 1);
        const float r1 = __shfl_xor(o1 ? a0[q] : a1[q], 1);
        float s = (o1 ? a1[q] : a0[q]) + r1;
        const float r2 = __shfl_xor(o1 ? a2[q] : a3[q], 1);
        float t = (o1 ? a3[q] : a2[q]) + r2;
        const bool o2 = (lane & 2);
        const float r3 = __shfl_xor(o2 ? s : t, 2);
        float u = (o2 ? t : s) + r3;                // residue lane&3 -> acc_{lane&3}
        u += __shfl_xor(u, 4);
        u += __shfl_xor(u, 8);
        u += __shfl_xor(u, 16);
        u += __shfl_xor(u, 32);
        if (lane < 4) projf[(size_t)(p0 + q) * 4 + lane] = u;
    }
}

// ---------------- kernel 2: pairwise NLL + finalize ----------------
// 256 blocks x 256 threads; 4 blocks per batch; sums the two proj halves.
__global__ __launch_bounds__(256) void loss_kernel(
        const int* __restrict__ mask,
        const float* __restrict__ proj,
        const float* __restrict__ bias,
        Ctrl* __restrict__ ctrl,
        float* __restrict__ out) {
    __shared__ float4 s_proj[LMAX];
    __shared__ float  s_w[4];
    __shared__ int    s_m[4];

    const int b   = blockIdx.x >> 2;
    const int q   = blockIdx.x & 3;
    const int tid = threadIdx.x;

    const float4* proj4 = (const float4*)proj;
    if (tid < LMAX) {
        const float4 pa = proj4[b * LMAX + tid];
        const float4 pb = proj4[NPOS + b * LMAX + tid];
        float4 v;
        v.x = pa.x + pb.x; v.y = pa.y + pb.y;
        v.z = pa.z + pb.z; v.w = pa.w + pb.w;
        s_proj[tid] = v;
    }

    int m = (tid < LMAX) ? mask[b * LMAX + tid] : 0;
    #pragma unroll
    for (int off = 32; off >= 1; off >>= 1) m += __shfl_xor(m, off);
    if ((tid & 63) == 0) s_m[tid >> 6] = m;
    __syncthreads();

    const int   T  = s_m[0] + s_m[1] + s_m[2] + s_m[3];
    const float b0 = bias[0];
    const float b1 = bias[1];

    float local = 0.f;
    const int tmax = T << 7;
    for (int t = q * 256 + tid; t < tmax; t += 1024) {
        const int j = t >> 7;
        const int k = t & (LMAX - 1);
        if (k < j) {
            const float4 pj = s_proj[j];
            const float4 pk = s_proj[k];
            const float l0 = pj.x + pk.z + b0;
            const float l1 = pj.y + pk.w + b1;
            const bool  pos = (k == j - 1);
            const float d  = pos ? (l0 - l1) : (l1 - l0);
            local += fmaxf(d, 0.f) + __logf(1.f + __expf(-fabsf(d)));
        }
    }

    #pragma unroll
    for (int off = 32; off >= 1; off >>= 1) local += __shfl_xor(local, off);
    if ((tid & 63) == 0) s_w[tid >> 6] = local;
    __syncthreads();

    if (tid == 0) {
        atomicAdd(&ctrl->accum, s_w[0] + s_w[1] + s_w[2] + s_w[3]);
        if (q == 0) atomicAdd(&ctrl->count, T * (T - 1) / 2);
        __threadfence();
        const int prev = atomicAdd(&ctrl->done2, 1);
        if (prev == 4 * BSZ - 1) {
            const float s = atomicAdd(&ctrl->accum, 0.0f);
            const int   c = atomicAdd(&ctrl->count, 0);
            out[0] = s / (float)(c > 1 ? c : 1);
        }
    }
}

extern "C" void kernel_launch(void* const* d_in, const int* in_sizes, int n_in,
                              void* d_out, int out_size, void* d_ws, size_t ws_size,
                              hipStream_t stream) {
    const float* enc  = (const float*)d_in[0];  // [BSZ, LMAX, DIM] fp32
    const int*   mask = (const int*)d_in[1];    // [BSZ, LMAX] int32
    const float* W    = (const float*)d_in[2];  // [2*DIM, 2] fp32
    const float* bias = (const float*)d_in[3];  // [2] fp32
    float* out = (float*)d_out;

    float* proj = (float*)d_ws;                          // 2*NPOS float4 = 256 KB
    Ctrl*  ctrl = (Ctrl*)((char*)d_ws + 2 * NPOS * 16);

    proj_kernel<<<NPOS / 8, 512, 0, stream>>>(enc, W, proj, ctrl);
    loss_kernel<<<4 * BSZ, 256, 0, stream>>>(mask, proj, bias, ctrl, out);
}

// Round 9
// 26.931 us; speedup vs baseline: 1.0313x; 1.0313x over previous
//
#include <hip/hip_runtime.h>

#define BSZ 64
#define LMAX 128
#define DIM 2048
#define NPOS (BSZ * LMAX)   // 8192

struct Ctrl {
    float accum;   // loss sum
    int   count;   // valid-pair count
    int   done2;   // finished loss-blocks
};

// ---------------- kernel 1: projections (+ ctrl init) ----------------
// 1024 blocks x 512 threads = 8 waves = 2 wave-quads. Each wave-quad owns 4
// consecutive positions; each wave covers a QUARTER row (512 dims) with its
// W-slice in registers (8 float4 = 32 VGPR). Depth-2 h prefetch. Target
// ~70-75 VGPR under the 85 cap of __launch_bounds__(512,6) -> 24 waves/CU.
// Four quarter-buffers; loss sums them.
__global__ __launch_bounds__(512, 6) void proj_kernel(
        const float* __restrict__ enc,
        const float* __restrict__ W,
        float* __restrict__ proj,      // [4][NPOS][4] floats
        Ctrl* __restrict__ ctrl) {
    if (blockIdx.x == 0 && threadIdx.x == 0) {
        ctrl->accum = 0.f; ctrl->count = 0; ctrl->done2 = 0;
    }

    const int tid  = threadIdx.x;
    const int wid  = tid >> 6;
    const int lane = tid & 63;
    const int quad = wid >> 2;                      // 0..1
    const int qw   = wid & 3;                       // quarter 0..3
    const int p0   = (blockIdx.x * 2 + quad) * 4;   // first of 4 positions

    // ---- W quarter-slice into registers: idx(it) = qw*128 + it*64 + lane ----
    const float4* __restrict__ W4 = (const float4*)W;   // [2*DIM,2] row-major
    float4 wl0[2], wl1[2], wr0[2], wr1[2];
    #pragma unroll
    for (int it = 0; it < 2; ++it) {
        const int idx = qw * 128 + it * 64 + lane;
        wl0[it] = W4[idx * 2];
        wl1[it] = W4[idx * 2 + 1];
        wr0[it] = W4[1024 + idx * 2];
        wr1[it] = W4[1024 + idx * 2 + 1];
    }

    const float4* __restrict__ h4 = (const float4*)enc;
    const size_t base = (size_t)p0 * (DIM / 4) + qw * 128 + lane;

    // prefetch position 0
    float4 hA0 = h4[base];
    float4 hA1 = h4[base + 64];

    float* __restrict__ projf = proj + (size_t)qw * NPOS * 4;

    #pragma unroll
    for (int q = 0; q < 4; ++q) {
        float4 hB0, hB1;
        if (q < 3) {
            const size_t nb = base + (size_t)(q + 1) * (DIM / 4);
            hB0 = h4[nb];
            hB1 = h4[nb + 64];
        }
        float a0, a1, a2, a3;
        a0 = hA0.x * wl0[0].x + hA0.y * wl0[0].z + hA0.z * wl1[0].x + hA0.w * wl1[0].z
           + hA1.x * wl0[1].x + hA1.y * wl0[1].z + hA1.z * wl1[1].x + hA1.w * wl1[1].z;
        a1 = hA0.x * wl0[0].y + hA0.y * wl0[0].w + hA0.z * wl1[0].y + hA0.w * wl1[0].w
           + hA1.x * wl0[1].y + hA1.y * wl0[1].w + hA1.z * wl1[1].y + hA1.w * wl1[1].w;
        a2 = hA0.x * wr0[0].x + hA0.y * wr0[0].z + hA0.z * wr1[0].x + hA0.w * wr1[0].z
           + hA1.x * wr0[1].x + hA1.y * wr0[1].z + hA1.z * wr1[1].x + hA1.w * wr1[1].z;
        a3 = hA0.x * wr0[0].y + hA0.y * wr0[0].w + hA0.z * wr1[0].y + hA0.w * wr1[0].w
           + hA1.x * wr0[1].y + hA1.y * wr0[1].w + hA1.z * wr1[1].y + hA1.w * wr1[1].w;

        // fold 4 accs to residue lane&3 (3 shfl), then 4-step butterfly
        const bool o1 = (lane & 1);
        const float r1 = __shfl_xor(o1 ? a0 : a1, 1);
        float s = (o1 ? a1 : a0) + r1;
        const float r2 = __shfl_xor(o1 ? a2 : a3, 1);
        float t = (o1 ? a3 : a2) + r2;
        const bool o2 = (lane & 2);
        const float r3 = __shfl_xor(o2 ? s : t, 2);
        float u = (o2 ? t : s) + r3;
        u += __shfl_xor(u, 4);
        u += __shfl_xor(u, 8);
        u += __shfl_xor(u, 16);
        u += __shfl_xor(u, 32);
        if (lane < 4) projf[(size_t)(p0 + q) * 4 + lane] = u;

        if (q < 3) { hA0 = hB0; hA1 = hB1; }
    }
}

// ---------------- kernel 2: pairwise NLL + finalize ----------------
// 256 blocks x 256 threads; 4 blocks per batch; sums the four proj quarters.
__global__ __launch_bounds__(256) void loss_kernel(
        const int* __restrict__ mask,
        const float* __restrict__ proj,
        const float* __restrict__ bias,
        Ctrl* __restrict__ ctrl,
        float* __restrict__ out) {
    __shared__ float4 s_proj[LMAX];
    __shared__ float  s_w[4];
    __shared__ int    s_m[4];

    const int b   = blockIdx.x >> 2;
    const int q   = blockIdx.x & 3;
    const int tid = threadIdx.x;

    const float4* proj4 = (const float4*)proj;
    if (tid < LMAX) {
        const float4 pa = proj4[0 * NPOS + b * LMAX + tid];
        const float4 pb = proj4[1 * NPOS + b * LMAX + tid];
        const float4 pc = proj4[2 * NPOS + b * LMAX + tid];
        const float4 pd = proj4[3 * NPOS + b * LMAX + tid];
        float4 v;
        v.x = (pa.x + pb.x) + (pc.x + pd.x);
        v.y = (pa.y + pb.y) + (pc.y + pd.y);
        v.z = (pa.z + pb.z) + (pc.z + pd.z);
        v.w = (pa.w + pb.w) + (pc.w + pd.w);
        s_proj[tid] = v;
    }

    int m = (tid < LMAX) ? mask[b * LMAX + tid] : 0;
    #pragma unroll
    for (int off = 32; off >= 1; off >>= 1) m += __shfl_xor(m, off);
    if ((tid & 63) == 0) s_m[tid >> 6] = m;
    __syncthreads();

    const int   T  = s_m[0] + s_m[1] + s_m[2] + s_m[3];
    const float b0 = bias[0];
    const float b1 = bias[1];

    float local = 0.f;
    const int tmax = T << 7;
    for (int t = q * 256 + tid; t < tmax; t += 1024) {
        const int j = t >> 7;
        const int k = t & (LMAX - 1);
        if (k < j) {
            const float4 pj = s_proj[j];
            const float4 pk = s_proj[k];
            const float l0 = pj.x + pk.z + b0;
            const float l1 = pj.y + pk.w + b1;
            const bool  pos = (k == j - 1);
            const float d  = pos ? (l0 - l1) : (l1 - l0);
            local += fmaxf(d, 0.f) + __logf(1.f + __expf(-fabsf(d)));
        }
    }

    #pragma unroll
    for (int off = 32; off >= 1; off >>= 1) local += __shfl_xor(local, off);
    if ((tid & 63) == 0) s_w[tid >> 6] = local;
    __syncthreads();

    if (tid == 0) {
        atomicAdd(&ctrl->accum, s_w[0] + s_w[1] + s_w[2] + s_w[3]);
        if (q == 0) atomicAdd(&ctrl->count, T * (T - 1) / 2);
        __threadfence();
        const int prev = atomicAdd(&ctrl->done2, 1);
        if (prev == 4 * BSZ - 1) {
            const float s = atomicAdd(&ctrl->accum, 0.0f);
            const int   c = atomicAdd(&ctrl->count, 0);
            out[0] = s / (float)(c > 1 ? c : 1);
        }
    }
}

extern "C" void kernel_launch(void* const* d_in, const int* in_sizes, int n_in,
                              void* d_out, int out_size, void* d_ws, size_t ws_size,
                              hipStream_t stream) {
    const float* enc  = (const float*)d_in[0];  // [BSZ, LMAX, DIM] fp32
    const int*   mask = (const int*)d_in[1];    // [BSZ, LMAX] int32
    const float* W    = (const float*)d_in[2];  // [2*DIM, 2] fp32
    const float* bias = (const float*)d_in[3];  // [2] fp32
    float* out = (float*)d_out;

    float* proj = (float*)d_ws;                          // 4*NPOS float4 = 512 KB
    Ctrl*  ctrl = (Ctrl*)((char*)d_ws + 4 * NPOS * 16);

    proj_kernel<<<NPOS / 8, 512, 0, stream>>>(enc, W, proj, ctrl);
    loss_kernel<<<4 * BSZ, 256, 0, stream>>>(mask, proj, bias, ctrl, out);
}